// Round 4
// baseline (493.074 us; speedup 1.0000x reference)
//
#include <hip/hip_runtime.h>

// B=8 S=1024 D=1024 H=16 DH=64.
// Head bh=b*16+s_hi (s_hi=s>>6); head elem (p,f) -> proj[b][s_hi*64+(p>>4)][(p&15)*64+f].
// mask index for head bh is s_hi&7. scale=0.5 (=> exp2 domain: 0.5*log2e).

typedef unsigned short u16;
typedef unsigned long long u64;
typedef __attribute__((ext_vector_type(8))) short bf16x8;
typedef __attribute__((ext_vector_type(4))) float f32x4;

#define MFMA_BF16(a, b, c) __builtin_amdgcn_mfma_f32_16x16x32_bf16((a), (b), (c), 0, 0, 0)

__device__ __forceinline__ u16 f2bf(float f) {
  unsigned u = __float_as_uint(f);
  u += 0x7fffu + ((u >> 16) & 1u);   // round-nearest-even
  return (u16)(u >> 16);
}
__device__ __forceinline__ float bf2f(u16 b) {
  return __uint_as_float(((unsigned)b) << 16);
}

static constexpr size_t MD = 8192ull * 1024ull;  // one [B,S,D] tensor, elements
static constexpr size_t DD = 1024ull * 1024ull;  // one [D,D] weight, elements
static constexpr float SCL = 0.72134752044f;     // 0.5 * log2(e)

// ---------------- f32 -> bf16 for key/value/query ----------------
__global__ __launch_bounds__(256) void cvt_k(const float* __restrict__ K,
                                             const float* __restrict__ V,
                                             const float* __restrict__ Q,
                                             u16* __restrict__ O) {
  const int z = blockIdx.z;
  const float* src = (z == 0) ? K : ((z == 1) ? V : Q);
  const size_t i = ((size_t)blockIdx.x * 256 + threadIdx.x) * 4;
  const float4 v = *reinterpret_cast<const float4*>(src + i);
  ushort4 o;
  o.x = f2bf(v.x); o.y = f2bf(v.y); o.z = f2bf(v.z); o.w = f2bf(v.w);
  *reinterpret_cast<ushort4*>(O + (size_t)z * MD + i) = o;
}

// ---------------- W[K,N] f32 -> WT[N,K] bf16, for Wk,Wv,Wq,Wf ----------------
__global__ __launch_bounds__(256) void wt_k(const float* __restrict__ Wk,
                                            const float* __restrict__ Wv,
                                            const float* __restrict__ Wq,
                                            const float* __restrict__ Wf,
                                            u16* __restrict__ WT) {
  const int z = blockIdx.z;
  const float* W = (z == 0) ? Wk : ((z == 1) ? Wv : ((z == 2) ? Wq : Wf));
  __shared__ float tile[32][33];
  const int k0 = blockIdx.y * 32, n0 = blockIdx.x * 32;
  const int r = threadIdx.x >> 5, c = threadIdx.x & 31;
#pragma unroll
  for (int rr = r; rr < 32; rr += 8)
    tile[rr][c] = W[(size_t)(k0 + rr) * 1024 + n0 + c];
  __syncthreads();
#pragma unroll
  for (int rr = r; rr < 32; rr += 8)
    WT[(size_t)z * DD + (size_t)(n0 + rr) * 1024 + k0 + c] = f2bf(tile[c][rr]);
}

// ---------------- mask -> bit-packed u64 words: mb[8][1024][16] ----------------
// Word w of row r of mask m covers cols w*64..w*64+63; bit c = mask nonzero.
__global__ __launch_bounds__(256) void mb_k(const unsigned char* __restrict__ mask8,
                                            u64* __restrict__ mb) {
  __shared__ int mflag;
  if (threadIdx.x == 0) {
    const unsigned* mw = reinterpret_cast<const unsigned*>(mask8);
    int allW = 1;  // storage is 4-byte words (int32 0/1 or f32 0.0/1.0)?
    for (int i = 0; i < 64; ++i) {
      const unsigned v = mw[i];
      if (v != 0u && v != 1u && v != 0x3F800000u) allW = 0;
    }
    mflag = allW;
  }
  __syncthreads();
  const int wide = mflag;
  const size_t wi = (size_t)blockIdx.x * 256 + threadIdx.x;  // word index
  const size_t src0 = wi * 64;                               // first element idx
  u64 bits = 0ull;
  if (!wide) {  // u8 bool storage
    const uint4* p = reinterpret_cast<const uint4*>(mask8 + src0);
#pragma unroll
    for (int q = 0; q < 4; ++q) {
      const uint4 v = p[q];
      const unsigned vv[4] = {v.x, v.y, v.z, v.w};
#pragma unroll
      for (int k = 0; k < 4; ++k) {
        unsigned tt = vv[k];
        tt |= tt >> 4; tt |= tt >> 2; tt |= tt >> 1;
        tt &= 0x01010101u;
        const unsigned nib =
            (tt & 1u) | ((tt >> 7) & 2u) | ((tt >> 14) & 4u) | ((tt >> 21) & 8u);
        bits |= (u64)nib << (q * 16 + k * 4);
      }
    }
  } else {  // 4-byte storage: nonzero word => masked
    const unsigned* p = reinterpret_cast<const unsigned*>(mask8) + src0;
#pragma unroll
    for (int k = 0; k < 64; ++k)
      bits |= (u64)(p[k] != 0u) << k;
  }
  mb[wi] = bits;
}

// ---------------- GEMM: C[M,N] = A[M,K] * BT[N,K]^T (+bias, epilogues) -------
// EPI==0: C -> bf16 (projections, z=0,1,2). EPI==1: C+resid -> f32 (final).
template <int EPI>
__global__ __launch_bounds__(256) void gemm_bt(
    const u16* __restrict__ A0, const u16* __restrict__ B0,
    const float* __restrict__ bias0, const float* __restrict__ bias1,
    const float* __restrict__ bias2, u16* __restrict__ Obf,
    float* __restrict__ Of, const float* __restrict__ resid) {
  __shared__ __align__(16) u16 As[128][40];  // +8 pad: conflict-spread, 16B rows
  __shared__ __align__(16) u16 Bs[128][40];
  const int z = blockIdx.z;
  const u16* A = A0 + (size_t)z * MD;
  const u16* Bt = B0 + (size_t)z * DD;
  const float* bias = (z == 0) ? bias0 : ((z == 1) ? bias1 : bias2);
  const int t = threadIdx.x;
  const int m0 = blockIdx.y * 128, n0 = blockIdx.x * 128;
  const int w = t >> 6, lane = t & 63, lr = lane & 15, lk = lane >> 4;
  const int wm = (w >> 1) * 64, wn = (w & 1) * 64;
  const int srow = t >> 2, scol = (t & 3) * 8;

  f32x4 acc[4][4] = {};

  for (int k0 = 0; k0 < 1024; k0 += 32) {
    const int4 a0 = *reinterpret_cast<const int4*>(A + (size_t)(m0 + srow) * 1024 + k0 + scol);
    const int4 a1 = *reinterpret_cast<const int4*>(A + (size_t)(m0 + srow + 64) * 1024 + k0 + scol);
    const int4 b0 = *reinterpret_cast<const int4*>(Bt + (size_t)(n0 + srow) * 1024 + k0 + scol);
    const int4 b1 = *reinterpret_cast<const int4*>(Bt + (size_t)(n0 + srow + 64) * 1024 + k0 + scol);
    __syncthreads();  // previous iter's fragment reads done before overwrite
    *reinterpret_cast<int4*>(&As[srow][scol]) = a0;
    *reinterpret_cast<int4*>(&As[srow + 64][scol]) = a1;
    *reinterpret_cast<int4*>(&Bs[srow][scol]) = b0;
    *reinterpret_cast<int4*>(&Bs[srow + 64][scol]) = b1;
    __syncthreads();
    bf16x8 af[4], bfr[4];
#pragma unroll
    for (int i = 0; i < 4; ++i)
      af[i] = *reinterpret_cast<const bf16x8*>(&As[wm + i * 16 + lr][lk * 8]);
#pragma unroll
    for (int j = 0; j < 4; ++j)
      bfr[j] = *reinterpret_cast<const bf16x8*>(&Bs[wn + j * 16 + lr][lk * 8]);
#pragma unroll
    for (int i = 0; i < 4; ++i) {
#pragma unroll
      for (int j = 0; j < 4; ++j)
        acc[i][j] = MFMA_BF16(af[i], bfr[j], acc[i][j]);
    }
  }

#pragma unroll
  for (int i = 0; i < 4; ++i) {
#pragma unroll
    for (int j = 0; j < 4; ++j) {
#pragma unroll
      for (int r = 0; r < 4; ++r) {
        const int row = m0 + wm + i * 16 + lk * 4 + r;  // C/D: row=(lane>>4)*4+reg
        const int col = n0 + wn + j * 16 + lr;          //       col=lane&15
        const float v = acc[i][j][r] + bias[col];
        if constexpr (EPI == 0) {
          Obf[(size_t)z * MD + (size_t)row * 1024 + col] = f2bf(v);
        } else {
          const size_t idx = (size_t)row * 1024 + col;
          Of[idx] = v + resid[idx];
        }
      }
    }
  }
}

// ---------------- V head-transpose: Vt[bh][f][p'] bf16 ----------------
__global__ __launch_bounds__(256) void vt_k(const u16* __restrict__ VP,
                                            u16* __restrict__ VTo) {
  __shared__ __align__(16) u16 tile[64][72];
  const int t = threadIdx.x;
  const int bh = blockIdx.y, p0 = blockIdx.x * 64;
  const int b = bh >> 4, shi = bh & 15;
  const size_t hb = (size_t)b * 1048576 + (size_t)shi * 65536;
#pragma unroll
  for (int it = 0; it < 2; ++it) {
    const int c = t + it * 256;
    const int row = c >> 3, f8 = (c & 7) * 8;
    const int p = p0 + row;
    *reinterpret_cast<int4*>(&tile[row][f8]) = *reinterpret_cast<const int4*>(
        VP + hb + (size_t)(p >> 4) * 1024 + (p & 15) * 64 + f8);
  }
  __syncthreads();
#pragma unroll
  for (int it = 0; it < 2; ++it) {
    const int c = t + it * 256;
    const int f = c >> 3, pc = (c & 7) * 8;
    __align__(16) u16 tmp[8];
#pragma unroll
    for (int i = 0; i < 8; ++i) tmp[i] = tile[pc + i][f];
    *reinterpret_cast<int4*>(VTo + (size_t)bh * 65536 + (size_t)f * 1024 + p0 + pc) =
        *reinterpret_cast<int4*>(tmp);
  }
}

// ---------------- fused attention, single-pass ----------------
// Grid (128, 64): bh = blockIdx.x (XCD-pinned head), q-tile of 16 rows = blockIdx.y.
// Ps is XOR-swizzled: element (q,k) lives at Ps[q*1024 + (k ^ ((q&7)<<3))].
// Bank-floor-optimal for phase-1 b64 writes, phase-2 b128 reads, phase-3 b64 reads.
__global__ __launch_bounds__(256, 4) void attn_k(
    const u16* __restrict__ QP, const u16* __restrict__ KP,
    const u16* __restrict__ VT, const u64* __restrict__ mb,
    float* __restrict__ attnOut, u16* __restrict__ ctx) {
  __shared__ __align__(16) u16 Ps[16 * 1024];
  __shared__ float red[4][16];

  const int t = threadIdx.x;
  const int bh = blockIdx.x;
  const int qt = blockIdx.y;
  const int q0 = qt * 16;
  const int b = bh >> 4, shi = bh & 15;
  const size_t hb = (size_t)b * 1048576 + (size_t)shi * 65536;
  const u64* mrow = mb + (size_t)(shi & 7) * 16384;  // [1024][16] words

  const int w = t >> 6, lane = t & 63, lr = lane & 15, lk = lane >> 4;

  // Q as B-fragments (same for all waves): lane holds Q[q0+lr][kd*32+lk*8+e]
  const u16* qbase = QP + hb + (size_t)qt * 1024 + lr * 64 + lk * 8;
  const bf16x8 qf0 = *reinterpret_cast<const bf16x8*>(qbase);
  const bf16x8 qf1 = *reinterpret_cast<const bf16x8*>(qbase + 32);

  float psum = 0.f;
  const int qsw = (lr & 7) << 3;  // phase-1/2 swizzle term (q = lr)

  // ---- phase 1: QK^T (transposed), exp2, pack to Ps ----
#pragma unroll
  for (int ki = 0; ki < 4; ++ki) {
    const int kt = w * 4 + ki;
    // K rows p=kt*64+j*16+lr -> addr hb + (kt*4+j)*1024 + lr*64 + col
    const u16* kb = KP + hb + (size_t)(kt * 4) * 1024 + lr * 64 + lk * 8;
    f32x4 sf[4];
#pragma unroll
    for (int j = 0; j < 4; ++j) {
      const bf16x8 k0 = *reinterpret_cast<const bf16x8*>(kb + j * 1024);
      const bf16x8 k1 = *reinterpret_cast<const bf16x8*>(kb + j * 1024 + 32);
      f32x4 a = {};
      a = MFMA_BF16(k0, qf0, a);
      a = MFMA_BF16(k1, qf1, a);
      sf[j] = a;  // C: row=k-local (j*16+lk*4+r), col=q=lr
    }
    const u64 mw = mrow[(size_t)(q0 + lr) * 16 + kt];
#pragma unroll
    for (int j = 0; j < 4; ++j) {
      u16 pb[4];
#pragma unroll
      for (int r = 0; r < 4; ++r) {
        const unsigned bit = (unsigned)(mw >> (j * 16 + lk * 4 + r)) & 1u;
        const float sel = bit ? -__builtin_inff() : 0.0f;
        const float p = __builtin_amdgcn_exp2f(fmaf(sf[j][r], SCL, sel));
        psum += p;
        pb[r] = f2bf(p);
      }
      const unsigned lo = (unsigned)pb[0] | ((unsigned)pb[1] << 16);
      const unsigned hi = (unsigned)pb[2] | ((unsigned)pb[3] << 16);
      const int kel = (kt * 64 + j * 16 + lk * 4) ^ qsw;  // swizzled element idx
      *reinterpret_cast<u64*>(&Ps[lr * 1024 + kel]) = (u64)lo | ((u64)hi << 32);
    }
  }
  // row-sum partial (this wave's 256-k slice) -> red[w][row]
  psum += __shfl_xor(psum, 16, 64);
  psum += __shfl_xor(psum, 32, 64);
  if (lane < 16) red[w][lr] = psum;
  __syncthreads();

  // ---- phase 2: PV. wave w -> ctx cols w*16..+15, rows q0..q0+15 ----
  const u16* vb = VT + (size_t)bh * 65536 + (size_t)(w * 16 + lr) * 1024 + lk * 8;
  f32x4 cacc[4] = {};   // 4 independent chains (ILP) over kk%4
#pragma unroll
  for (int kk = 0; kk < 32; ++kk) {
    const int kel = (kk * 32 + lk * 8) ^ qsw;
    const bf16x8 pf = *reinterpret_cast<const bf16x8*>(&Ps[lr * 1024 + kel]);
    const bf16x8 vf = *reinterpret_cast<const bf16x8*>(vb + kk * 32);
    cacc[kk & 3] = MFMA_BF16(pf, vf, cacc[kk & 3]);
  }
#pragma unroll
  for (int r = 0; r < 4; ++r) {
    const int q = lk * 4 + r;
    const float rs = red[0][q] + red[1][q] + red[2][q] + red[3][q];
    const float ri = (rs > 0.f) ? __builtin_amdgcn_rcpf(rs) : 0.f;
    const float cv = cacc[0][r] + cacc[1][r] + cacc[2][r] + cacc[3][r];
    ctx[hb + (size_t)qt * 1024 + (size_t)q * 64 + w * 16 + lr] = f2bf(cv * ri);
  }

  // ---- phase 3: attnOut = Ps * rinv, coalesced float4 stores ----
  const int arow = t >> 4, ac4 = (t & 15) * 4;
  const int asw = (arow & 7) << 3;
  const float rsA = red[0][arow] + red[1][arow] + red[2][arow] + red[3][arow];
  const float riA = (rsA > 0.f) ? __builtin_amdgcn_rcpf(rsA) : 0.f;
  float* aout = attnOut + (size_t)bh * 1048576 + (size_t)(q0 + arow) * 1024;
#pragma unroll
  for (int i = 0; i < 16; ++i) {
    const int col = i * 64 + ac4;
    const u64 p4 = *reinterpret_cast<const u64*>(&Ps[arow * 1024 + (col ^ asw)]);
    float4 o;
    o.x = bf2f((u16)(p4 & 0xffffu)) * riA;
    o.y = bf2f((u16)((p4 >> 16) & 0xffffu)) * riA;
    o.z = bf2f((u16)((p4 >> 32) & 0xffffu)) * riA;
    o.w = bf2f((u16)(p4 >> 48)) * riA;
    *reinterpret_cast<float4*>(aout + col) = o;
  }
}

// ---------------- LayerNorm over last dim (1024) ----------------
__global__ __launch_bounds__(256) void ln_k(const float* __restrict__ X,
                                            const float* __restrict__ gamma,
                                            const float* __restrict__ beta,
                                            float* __restrict__ Y) {
  const int row = blockIdx.x, t = threadIdx.x;
  const size_t base = (size_t)row * 1024;
  const float4 x = *reinterpret_cast<const float4*>(X + base + t * 4);
  float s = x.x + x.y + x.z + x.w;
  float s2 = x.x * x.x + x.y * x.y + x.z * x.z + x.w * x.w;
#pragma unroll
  for (int d = 1; d < 64; d <<= 1) {
    s += __shfl_xor(s, d, 64);
    s2 += __shfl_xor(s2, d, 64);
  }
  __shared__ float red[8];
  const int w = t >> 6;
  if ((t & 63) == 0) { red[w] = s; red[4 + w] = s2; }
  __syncthreads();
  s = red[0] + red[1] + red[2] + red[3];
  s2 = red[4] + red[5] + red[6] + red[7];
  const float mu = s * (1.f / 1024.f);
  const float var = s2 * (1.f / 1024.f) - mu * mu;
  const float inv = rsqrtf(var + 1e-5f);
  const float4 g = *reinterpret_cast<const float4*>(gamma + t * 4);
  const float4 be = *reinterpret_cast<const float4*>(beta + t * 4);
  float4 y;
  y.x = (x.x - mu) * inv * g.x + be.x;
  y.y = (x.y - mu) * inv * g.y + be.y;
  y.z = (x.z - mu) * inv * g.z + be.z;
  y.w = (x.w - mu) * inv * g.w + be.w;
  *reinterpret_cast<float4*>(Y + base + t * 4) = y;
}

extern "C" void kernel_launch(void* const* d_in, const int* in_sizes, int n_in,
                              void* d_out, int out_size, void* d_ws, size_t ws_size,
                              hipStream_t stream) {
  const float* keyF = (const float*)d_in[0];
  const float* valueF = (const float*)d_in[1];
  const float* queryF = (const float*)d_in[2];
  const unsigned char* mask8 = (const unsigned char*)d_in[3];
  const float* Wk = (const float*)d_in[4];
  const float* bk = (const float*)d_in[5];
  const float* Wv = (const float*)d_in[6];
  const float* bv = (const float*)d_in[7];
  const float* Wq = (const float*)d_in[8];
  const float* bq = (const float*)d_in[9];
  const float* Wf = (const float*)d_in[10];
  const float* bfp = (const float*)d_in[11];
  const float* gamma = (const float*)d_in[12];
  const float* beta = (const float*)d_in[13];

  char* ws = (char*)d_ws;
  // layout (bytes): [0,48M) Xbf k/v/q bf16 | [48M,56M) WT x4 | [56M,104M) K/V/Q proj
  // | [104M,120M) Vt | [120M,121M) mask bits. After projections: [0,16M) ctx,
  // [16M,48M) preLN f32.
  u16* Xbf = (u16*)(ws);
  u16* WT = (u16*)(ws + 50331648);
  u16* KP = (u16*)(ws + 58720256);
  u16* VP = (u16*)(ws + 75497472);
  u16* QP = (u16*)(ws + 92274688);
  u16* VT = (u16*)(ws + 109051904);
  u64* MB = (u64*)(ws + 125829120);
  u16* CTX = (u16*)(ws);
  float* PRELN = (float*)(ws + 16777216);

  float* outF = (float*)d_out;
  float* attnF = outF + 8388608;

  cvt_k<<<dim3(8192, 1, 3), 256, 0, stream>>>(keyF, valueF, queryF, Xbf);
  wt_k<<<dim3(32, 32, 4), 256, 0, stream>>>(Wk, Wv, Wq, Wf, WT);
  mb_k<<<dim3(512), 256, 0, stream>>>(mask8, MB);
  gemm_bt<0><<<dim3(8, 64, 3), 256, 0, stream>>>(Xbf, WT, bk, bv, bq, KP, nullptr, nullptr);
  vt_k<<<dim3(16, 128), 256, 0, stream>>>(VP, VT);
  attn_k<<<dim3(128, 64), 256, 0, stream>>>(QP, KP, VT, MB, attnF, CTX);
  gemm_bt<1><<<dim3(8, 64, 1), 256, 0, stream>>>(CTX, WT + 3 * DD, bfp, bfp, bfp,
                                                 nullptr, PRELN, queryF);
  ln_k<<<dim3(8192), 256, 0, stream>>>(PRELN, gamma, beta, outF);
}

// Round 6
// 454.270 us; speedup vs baseline: 1.0854x; 1.0854x over previous
//
#include <hip/hip_runtime.h>

// B=8 S=1024 D=1024 H=16 DH=64.
// Head bh=b*16+s_hi (s_hi=s>>6); head elem (p,f) -> proj[b][s_hi*64+(p>>4)][(p&15)*64+f].
// mask index for head bh is s_hi&7. scale=0.5 (=> exp2 domain: 0.5*log2e).

typedef unsigned short u16;
typedef unsigned long long u64;
typedef __attribute__((ext_vector_type(8))) short bf16x8;
typedef __attribute__((ext_vector_type(4))) float f32x4;

#define MFMA_BF16(a, b, c) __builtin_amdgcn_mfma_f32_16x16x32_bf16((a), (b), (c), 0, 0, 0)

__device__ __forceinline__ u16 f2bf(float f) {
  unsigned u = __float_as_uint(f);
  u += 0x7fffu + ((u >> 16) & 1u);   // round-nearest-even
  return (u16)(u >> 16);
}
__device__ __forceinline__ float bf2f(u16 b) {
  return __uint_as_float(((unsigned)b) << 16);
}
__device__ __forceinline__ void gload_lds16(const u16* g, u16* l) {
  __builtin_amdgcn_global_load_lds(
      (const __attribute__((address_space(1))) void*)g,
      (__attribute__((address_space(3))) void*)l, 16, 0, 0);
}

static constexpr size_t MD = 8192ull * 1024ull;  // one [B,S,D] tensor, elements
static constexpr size_t DD = 1024ull * 1024ull;  // one [D,D] weight, elements
static constexpr float SCL = 0.72134752044f;     // 0.5 * log2(e)

// ---------------- f32 -> bf16 for key/value/query ----------------
__global__ __launch_bounds__(256) void cvt_k(const float* __restrict__ K,
                                             const float* __restrict__ V,
                                             const float* __restrict__ Q,
                                             u16* __restrict__ O) {
  const int z = blockIdx.z;
  const float* src = (z == 0) ? K : ((z == 1) ? V : Q);
  const size_t i = ((size_t)blockIdx.x * 256 + threadIdx.x) * 4;
  const float4 v = *reinterpret_cast<const float4*>(src + i);
  ushort4 o;
  o.x = f2bf(v.x); o.y = f2bf(v.y); o.z = f2bf(v.z); o.w = f2bf(v.w);
  *reinterpret_cast<ushort4*>(O + (size_t)z * MD + i) = o;
}

// ---------------- W[K,N] f32 -> WT[N,K] bf16, for Wk,Wv,Wq,Wf ----------------
__global__ __launch_bounds__(256) void wt_k(const float* __restrict__ Wk,
                                            const float* __restrict__ Wv,
                                            const float* __restrict__ Wq,
                                            const float* __restrict__ Wf,
                                            u16* __restrict__ WT) {
  const int z = blockIdx.z;
  const float* W = (z == 0) ? Wk : ((z == 1) ? Wv : ((z == 2) ? Wq : Wf));
  __shared__ float tile[32][33];
  const int k0 = blockIdx.y * 32, n0 = blockIdx.x * 32;
  const int r = threadIdx.x >> 5, c = threadIdx.x & 31;
#pragma unroll
  for (int rr = r; rr < 32; rr += 8)
    tile[rr][c] = W[(size_t)(k0 + rr) * 1024 + n0 + c];
  __syncthreads();
#pragma unroll
  for (int rr = r; rr < 32; rr += 8)
    WT[(size_t)z * DD + (size_t)(n0 + rr) * 1024 + k0 + c] = f2bf(tile[c][rr]);
}

// ---------------- mask -> bit-packed u64 words: mb[8][1024][16] ----------------
__global__ __launch_bounds__(256) void mb_k(const unsigned char* __restrict__ mask8,
                                            u64* __restrict__ mb) {
  __shared__ int mflag;
  if (threadIdx.x == 0) {
    const unsigned* mw = reinterpret_cast<const unsigned*>(mask8);
    int allW = 1;  // storage is 4-byte words (int32 0/1 or f32 0.0/1.0)?
    for (int i = 0; i < 64; ++i) {
      const unsigned v = mw[i];
      if (v != 0u && v != 1u && v != 0x3F800000u) allW = 0;
    }
    mflag = allW;
  }
  __syncthreads();
  const int wide = mflag;
  const size_t wi = (size_t)blockIdx.x * 256 + threadIdx.x;  // word index
  const size_t src0 = wi * 64;                               // first element idx
  u64 bits = 0ull;
  if (!wide) {  // u8 bool storage
    const uint4* p = reinterpret_cast<const uint4*>(mask8 + src0);
#pragma unroll
    for (int q = 0; q < 4; ++q) {
      const uint4 v = p[q];
      const unsigned vv[4] = {v.x, v.y, v.z, v.w};
#pragma unroll
      for (int k = 0; k < 4; ++k) {
        unsigned tt = vv[k];
        tt |= tt >> 4; tt |= tt >> 2; tt |= tt >> 1;
        tt &= 0x01010101u;
        const unsigned nib =
            (tt & 1u) | ((tt >> 7) & 2u) | ((tt >> 14) & 4u) | ((tt >> 21) & 8u);
        bits |= (u64)nib << (q * 16 + k * 4);
      }
    }
  } else {  // 4-byte storage: nonzero word => masked
    const unsigned* p = reinterpret_cast<const unsigned*>(mask8) + src0;
#pragma unroll
    for (int k = 0; k < 64; ++k)
      bits |= (u64)(p[k] != 0u) << k;
  }
  mb[wi] = bits;
}

// ---------------- GEMM (m97 pattern): C = A * BT^T (+bias, epilogues) -------
// Linear LDS [128][32], global_load_lds width-16, ds_read_b128 fragments.
// EPI==0: C -> bf16 (projections, z=0,1,2). EPI==1: C+resid -> f32 (final).
template <int EPI>
__global__ __launch_bounds__(256) void gemm_bt(
    const u16* __restrict__ A0, const u16* __restrict__ B0,
    const float* __restrict__ bias0, const float* __restrict__ bias1,
    const float* __restrict__ bias2, u16* __restrict__ Obf,
    float* __restrict__ Of, const float* __restrict__ resid) {
  __shared__ __align__(16) u16 As[128 * 32];  // 64B per row, linear (gload_lds dest)
  __shared__ __align__(16) u16 Bs[128 * 32];
  const int z = blockIdx.z;
  const u16* A = A0 + (size_t)z * MD;
  const u16* Bt = B0 + (size_t)z * DD;
  const float* bias = (z == 0) ? bias0 : ((z == 1) ? bias1 : bias2);
  const int t = threadIdx.x;
  const int m0 = blockIdx.y * 128, n0 = blockIdx.x * 128;
  const int w = t >> 6, lane = t & 63, lr = lane & 15, lk = lane >> 4;
  const int wm = (w >> 1) * 64, wn = (w & 1) * 64;
  const int srow = lane >> 2, scol = (lane & 3) * 8;  // within 16-row chunk

  f32x4 acc[4][4] = {};

  for (int k0 = 0; k0 < 1024; k0 += 32) {
    __syncthreads();  // previous iter's fragment reads done before overwrite
#pragma unroll
    for (int it = 0; it < 2; ++it) {
      const int c = w * 2 + it;  // chunk = 16 rows; wave-uniform LDS base
      gload_lds16(A + (size_t)(m0 + 16 * c + srow) * 1024 + k0 + scol,
                  &As[c * 512 + lane * 8]);
      gload_lds16(Bt + (size_t)(n0 + 16 * c + srow) * 1024 + k0 + scol,
                  &Bs[c * 512 + lane * 8]);
    }
    __syncthreads();  // barrier drain waits vmcnt(0): LDS tiles ready
    bf16x8 af[4], bfr[4];
#pragma unroll
    for (int i = 0; i < 4; ++i)
      af[i] = *reinterpret_cast<const bf16x8*>(&As[(wm + i * 16 + lr) * 32 + lk * 8]);
#pragma unroll
    for (int j = 0; j < 4; ++j)
      bfr[j] = *reinterpret_cast<const bf16x8*>(&Bs[(wn + j * 16 + lr) * 32 + lk * 8]);
#pragma unroll
    for (int i = 0; i < 4; ++i) {
#pragma unroll
      for (int j = 0; j < 4; ++j)
        acc[i][j] = MFMA_BF16(af[i], bfr[j], acc[i][j]);
    }
  }

#pragma unroll
  for (int i = 0; i < 4; ++i) {
#pragma unroll
    for (int j = 0; j < 4; ++j) {
#pragma unroll
      for (int r = 0; r < 4; ++r) {
        const int row = m0 + wm + i * 16 + lk * 4 + r;  // C/D: row=(lane>>4)*4+reg
        const int col = n0 + wn + j * 16 + lr;          //       col=lane&15
        const float v = acc[i][j][r] + bias[col];
        if constexpr (EPI == 0) {
          Obf[(size_t)z * MD + (size_t)row * 1024 + col] = f2bf(v);
        } else {
          const size_t idx = (size_t)row * 1024 + col;
          Of[idx] = v + resid[idx];
        }
      }
    }
  }
}

// ---------------- V head-transpose: Vt[bh][f][p'] bf16 ----------------
__global__ __launch_bounds__(256) void vt_k(const u16* __restrict__ VP,
                                            u16* __restrict__ VTo) {
  __shared__ __align__(16) u16 tile[64][72];
  const int t = threadIdx.x;
  const int bh = blockIdx.y, p0 = blockIdx.x * 64;
  const int b = bh >> 4, shi = bh & 15;
  const size_t hb = (size_t)b * 1048576 + (size_t)shi * 65536;
#pragma unroll
  for (int it = 0; it < 2; ++it) {
    const int c = t + it * 256;
    const int row = c >> 3, f8 = (c & 7) * 8;
    const int p = p0 + row;
    *reinterpret_cast<int4*>(&tile[row][f8]) = *reinterpret_cast<const int4*>(
        VP + hb + (size_t)(p >> 4) * 1024 + (p & 15) * 64 + f8);
  }
  __syncthreads();
#pragma unroll
  for (int it = 0; it < 2; ++it) {
    const int c = t + it * 256;
    const int f = c >> 3, pc = (c & 7) * 8;
    __align__(16) u16 tmp[8];
#pragma unroll
    for (int i = 0; i < 8; ++i) tmp[i] = tile[pc + i][f];
    *reinterpret_cast<int4*>(VTo + (size_t)bh * 65536 + (size_t)f * 1024 + p0 + pc) =
        *reinterpret_cast<int4*>(tmp);
  }
}

// ---------------- fused attention, single-pass, wave-specialized ----------------
// Grid (128, 64), 512 threads (8 waves). bh = blockIdx.x, 16 q-rows per block.
// Phase 1: wave w computes k-slice [w*128, w*128+128): S^T = mfma(K,Q) (thread owns
// q-row lr), p = exp2(fma(s,SCL, mask?-inf:0)) unnormalized -> swizzled Ps (LDS).
// One barrier. Then waves 0-3: PV + ctx (normalized); waves 4-7: attnOut streaming
// (normalized, nontemporal) CONCURRENTLY.
__global__ __launch_bounds__(512) void attn_k(
    const u16* __restrict__ QP, const u16* __restrict__ KP,
    const u16* __restrict__ VT, const u64* __restrict__ mb,
    float* __restrict__ attnOut, u16* __restrict__ ctx) {
  __shared__ __align__(16) u16 Ps[16 * 1024];  // (q,k) at Ps[q*1024 + (k^((q&7)<<3))]
  __shared__ float red[8][16];

  const int t = threadIdx.x;
  const int bh = blockIdx.x;
  const int qt = blockIdx.y;
  const int q0 = qt * 16;
  const int b = bh >> 4, shi = bh & 15;
  const size_t hb = (size_t)b * 1048576 + (size_t)shi * 65536;
  const u64* mrow = mb + (size_t)(shi & 7) * 16384;  // [1024][16] words

  const int w = t >> 6, lane = t & 63, lr = lane & 15, lk = lane >> 4;
  const int qsw = (lr & 7) << 3;  // swizzle term (q = lr)

  // Q as B-fragments: lane holds Q[q0+lr][kd*32+lk*8+e]
  const u16* qbase = QP + hb + (size_t)qt * 1024 + lr * 64 + lk * 8;
  const bf16x8 qf0 = *reinterpret_cast<const bf16x8*>(qbase);
  const bf16x8 qf1 = *reinterpret_cast<const bf16x8*>(qbase + 32);

  float psum = 0.f;

  // ---- phase 1: QK^T (transposed), exp2, pack to Ps. wave w: kt = 2w, 2w+1 ----
#pragma unroll
  for (int ki = 0; ki < 2; ++ki) {
    const int kt = w * 2 + ki;
    // K rows p=kt*64+j*16+lr -> addr hb + (kt*4+j)*1024 + lr*64 + col
    const u16* kb = KP + hb + (size_t)(kt * 4) * 1024 + lr * 64 + lk * 8;
    f32x4 sf[4];
#pragma unroll
    for (int j = 0; j < 4; ++j) {
      const bf16x8 k0 = *reinterpret_cast<const bf16x8*>(kb + j * 1024);
      const bf16x8 k1 = *reinterpret_cast<const bf16x8*>(kb + j * 1024 + 32);
      f32x4 a = {};
      a = MFMA_BF16(k0, qf0, a);
      a = MFMA_BF16(k1, qf1, a);
      sf[j] = a;  // C: row=k-local (j*16+lk*4+r), col=q=lr
    }
    const u64 mw = mrow[(size_t)(q0 + lr) * 16 + kt];
#pragma unroll
    for (int j = 0; j < 4; ++j) {
      u16 pb[4];
#pragma unroll
      for (int r = 0; r < 4; ++r) {
        const unsigned bit = (unsigned)(mw >> (j * 16 + lk * 4 + r)) & 1u;
        const float sel = bit ? -__builtin_inff() : 0.0f;
        const float p = __builtin_amdgcn_exp2f(fmaf(sf[j][r], SCL, sel));
        psum += p;
        pb[r] = f2bf(p);
      }
      const unsigned lo = (unsigned)pb[0] | ((unsigned)pb[1] << 16);
      const unsigned hi = (unsigned)pb[2] | ((unsigned)pb[3] << 16);
      const int kel = (kt * 64 + j * 16 + lk * 4) ^ qsw;  // swizzled element idx
      *reinterpret_cast<u64*>(&Ps[lr * 1024 + kel]) = (u64)lo | ((u64)hi << 32);
    }
  }
  // row-sum partial (this wave's 128-k slice) -> red[w][row]
  psum += __shfl_xor(psum, 16, 64);
  psum += __shfl_xor(psum, 32, 64);
  if (lane < 16) red[w][lr] = psum;
  __syncthreads();

  if (w < 4) {
    // ---- phase 2 (waves 0-3): PV. wave w -> ctx cols w*16..+15 ----
    const u16* vb = VT + (size_t)bh * 65536 + (size_t)(w * 16 + lr) * 1024 + lk * 8;
    f32x4 cacc[4] = {};  // 4 independent chains (ILP) over kk%4
#pragma unroll
    for (int kk = 0; kk < 32; ++kk) {
      const int kel = (kk * 32 + lk * 8) ^ qsw;
      const bf16x8 pf = *reinterpret_cast<const bf16x8*>(&Ps[lr * 1024 + kel]);
      const bf16x8 vf = *reinterpret_cast<const bf16x8*>(vb + kk * 32);
      cacc[kk & 3] = MFMA_BF16(pf, vf, cacc[kk & 3]);
    }
#pragma unroll
    for (int r = 0; r < 4; ++r) {
      const int q = lk * 4 + r;
      const float rs = red[0][q] + red[1][q] + red[2][q] + red[3][q] +
                       red[4][q] + red[5][q] + red[6][q] + red[7][q];
      const float ri = (rs > 0.f) ? __builtin_amdgcn_rcpf(rs) : 0.f;
      const float cv = cacc[0][r] + cacc[1][r] + cacc[2][r] + cacc[3][r];
      ctx[hb + (size_t)qt * 1024 + (size_t)q * 64 + w * 16 + lr] = f2bf(cv * ri);
    }
  } else {
    // ---- phase 3 (waves 4-7): attnOut = Ps * rinv, nontemporal f32x4 ----
    const int t2 = t - 256;
    const int arow = t2 >> 4, ac4 = (t2 & 15) * 4;
    const int asw = (arow & 7) << 3;
    const float rsA = red[0][arow] + red[1][arow] + red[2][arow] + red[3][arow] +
                      red[4][arow] + red[5][arow] + red[6][arow] + red[7][arow];
    const float riA = (rsA > 0.f) ? __builtin_amdgcn_rcpf(rsA) : 0.f;
    float* aout = attnOut + (size_t)bh * 1048576 + (size_t)(q0 + arow) * 1024;
#pragma unroll
    for (int i = 0; i < 16; ++i) {
      const int col = i * 64 + ac4;
      const u64 p4 = *reinterpret_cast<const u64*>(&Ps[arow * 1024 + (col ^ asw)]);
      f32x4 o;
      o[0] = bf2f((u16)(p4 & 0xffffu)) * riA;
      o[1] = bf2f((u16)((p4 >> 16) & 0xffffu)) * riA;
      o[2] = bf2f((u16)((p4 >> 32) & 0xffffu)) * riA;
      o[3] = bf2f((u16)(p4 >> 48)) * riA;
      __builtin_nontemporal_store(o, reinterpret_cast<f32x4*>(aout + col));
    }
  }
}

// ---------------- LayerNorm over last dim (1024) ----------------
__global__ __launch_bounds__(256) void ln_k(const float* __restrict__ X,
                                            const float* __restrict__ gamma,
                                            const float* __restrict__ beta,
                                            float* __restrict__ Y) {
  const int row = blockIdx.x, t = threadIdx.x;
  const size_t base = (size_t)row * 1024;
  const float4 x = *reinterpret_cast<const float4*>(X + base + t * 4);
  float s = x.x + x.y + x.z + x.w;
  float s2 = x.x * x.x + x.y * x.y + x.z * x.z + x.w * x.w;
#pragma unroll
  for (int d = 1; d < 64; d <<= 1) {
    s += __shfl_xor(s, d, 64);
    s2 += __shfl_xor(s2, d, 64);
  }
  __shared__ float red[8];
  const int w = t >> 6;
  if ((t & 63) == 0) { red[w] = s; red[4 + w] = s2; }
  __syncthreads();
  s = red[0] + red[1] + red[2] + red[3];
  s2 = red[4] + red[5] + red[6] + red[7];
  const float mu = s * (1.f / 1024.f);
  const float var = s2 * (1.f / 1024.f) - mu * mu;
  const float inv = rsqrtf(var + 1e-5f);
  const float4 g = *reinterpret_cast<const float4*>(gamma + t * 4);
  const float4 be = *reinterpret_cast<const float4*>(beta + t * 4);
  float4 y;
  y.x = (x.x - mu) * inv * g.x + be.x;
  y.y = (x.y - mu) * inv * g.y + be.y;
  y.z = (x.z - mu) * inv * g.z + be.z;
  y.w = (x.w - mu) * inv * g.w + be.w;
  *reinterpret_cast<float4*>(Y + base + t * 4) = y;
}

extern "C" void kernel_launch(void* const* d_in, const int* in_sizes, int n_in,
                              void* d_out, int out_size, void* d_ws, size_t ws_size,
                              hipStream_t stream) {
  const float* keyF = (const float*)d_in[0];
  const float* valueF = (const float*)d_in[1];
  const float* queryF = (const float*)d_in[2];
  const unsigned char* mask8 = (const unsigned char*)d_in[3];
  const float* Wk = (const float*)d_in[4];
  const float* bk = (const float*)d_in[5];
  const float* Wv = (const float*)d_in[6];
  const float* bv = (const float*)d_in[7];
  const float* Wq = (const float*)d_in[8];
  const float* bq = (const float*)d_in[9];
  const float* Wf = (const float*)d_in[10];
  const float* bfp = (const float*)d_in[11];
  const float* gamma = (const float*)d_in[12];
  const float* beta = (const float*)d_in[13];

  char* ws = (char*)d_ws;
  // layout (bytes): [0,48M) Xbf k/v/q bf16 | [48M,56M) WT x4 | [56M,104M) K/V/Q proj
  // | [104M,120M) Vt | [120M,121M) mask bits. After projections: [0,16M) ctx,
  // [16M,48M) preLN f32.
  u16* Xbf = (u16*)(ws);
  u16* WT = (u16*)(ws + 50331648);
  u16* KP = (u16*)(ws + 58720256);
  u16* VP = (u16*)(ws + 75497472);
  u16* QP = (u16*)(ws + 92274688);
  u16* VT = (u16*)(ws + 109051904);
  u64* MB = (u64*)(ws + 125829120);
  u16* CTX = (u16*)(ws);
  float* PRELN = (float*)(ws + 16777216);

  float* outF = (float*)d_out;
  float* attnF = outF + 8388608;

  cvt_k<<<dim3(8192, 1, 3), 256, 0, stream>>>(keyF, valueF, queryF, Xbf);
  wt_k<<<dim3(32, 32, 4), 256, 0, stream>>>(Wk, Wv, Wq, Wf, WT);
  mb_k<<<dim3(512), 256, 0, stream>>>(mask8, MB);
  gemm_bt<0><<<dim3(8, 64, 3), 256, 0, stream>>>(Xbf, WT, bk, bv, bq, KP, nullptr, nullptr);
  vt_k<<<dim3(16, 128), 256, 0, stream>>>(VP, VT);
  attn_k<<<dim3(128, 64), 512, 0, stream>>>(QP, KP, VT, MB, attnF, CTX);
  gemm_bt<1><<<dim3(8, 64, 1), 256, 0, stream>>>(CTX, WT + 3 * DD, bfp, bfp, bfp,
                                                 nullptr, PRELN, queryF);
  ln_k<<<dim3(8192), 256, 0, stream>>>(PRELN, gamma, beta, outF);
}

// Round 7
// 398.480 us; speedup vs baseline: 1.2374x; 1.1400x over previous
//
#include <hip/hip_runtime.h>

// B=8 S=1024 D=1024 H=16 DH=64.
// Head bh=b*16+s_hi (s_hi=s>>6); head elem (p,f) -> proj[b][s_hi*64+(p>>4)][(p&15)*64+f].
// mask index for head bh is s_hi&7. scale=0.5 (=> exp2 domain: 0.5*log2e).

typedef unsigned short u16;
typedef unsigned long long u64;
typedef __attribute__((ext_vector_type(8))) short bf16x8;
typedef __attribute__((ext_vector_type(4))) float f32x4;

#define MFMA_BF16(a, b, c) __builtin_amdgcn_mfma_f32_16x16x32_bf16((a), (b), (c), 0, 0, 0)

__device__ __forceinline__ u16 f2bf(float f) {
  unsigned u = __float_as_uint(f);
  u += 0x7fffu + ((u >> 16) & 1u);   // round-nearest-even
  return (u16)(u >> 16);
}
__device__ __forceinline__ float bf2f(u16 b) {
  return __uint_as_float(((unsigned)b) << 16);
}
__device__ __forceinline__ void gload_lds16(const u16* g, u16* l) {
  __builtin_amdgcn_global_load_lds(
      (const __attribute__((address_space(1))) void*)g,
      (__attribute__((address_space(3))) void*)l, 16, 0, 0);
}

static constexpr size_t MD = 8192ull * 1024ull;  // one [B,S,D] tensor, elements
static constexpr size_t DD = 1024ull * 1024ull;  // one [D,D] weight, elements
static constexpr float SCL = 0.72134752044f;     // 0.5 * log2(e)

// ---------------- f32 -> bf16 for key/value/query ----------------
__global__ __launch_bounds__(256) void cvt_k(const float* __restrict__ K,
                                             const float* __restrict__ V,
                                             const float* __restrict__ Q,
                                             u16* __restrict__ O) {
  const int z = blockIdx.z;
  const float* src = (z == 0) ? K : ((z == 1) ? V : Q);
  const size_t i = ((size_t)blockIdx.x * 256 + threadIdx.x) * 4;
  const float4 v = *reinterpret_cast<const float4*>(src + i);
  ushort4 o;
  o.x = f2bf(v.x); o.y = f2bf(v.y); o.z = f2bf(v.z); o.w = f2bf(v.w);
  *reinterpret_cast<ushort4*>(O + (size_t)z * MD + i) = o;
}

// ---------------- W[K,N] f32 -> WT[N,K] bf16, for Wk,Wv,Wq,Wf ----------------
__global__ __launch_bounds__(256) void wt_k(const float* __restrict__ Wk,
                                            const float* __restrict__ Wv,
                                            const float* __restrict__ Wq,
                                            const float* __restrict__ Wf,
                                            u16* __restrict__ WT) {
  const int z = blockIdx.z;
  const float* W = (z == 0) ? Wk : ((z == 1) ? Wv : ((z == 2) ? Wq : Wf));
  __shared__ float tile[32][33];
  const int k0 = blockIdx.y * 32, n0 = blockIdx.x * 32;
  const int r = threadIdx.x >> 5, c = threadIdx.x & 31;
#pragma unroll
  for (int rr = r; rr < 32; rr += 8)
    tile[rr][c] = W[(size_t)(k0 + rr) * 1024 + n0 + c];
  __syncthreads();
#pragma unroll
  for (int rr = r; rr < 32; rr += 8)
    WT[(size_t)z * DD + (size_t)(n0 + rr) * 1024 + k0 + c] = f2bf(tile[c][rr]);
}

// ---------------- mask -> bit-packed u64 words: mb[8][1024][16] ----------------
__global__ __launch_bounds__(256) void mb_k(const unsigned char* __restrict__ mask8,
                                            u64* __restrict__ mb) {
  __shared__ int mflag;
  if (threadIdx.x == 0) {
    const unsigned* mw = reinterpret_cast<const unsigned*>(mask8);
    int allW = 1;  // storage is 4-byte words (int32 0/1 or f32 0.0/1.0)?
    for (int i = 0; i < 64; ++i) {
      const unsigned v = mw[i];
      if (v != 0u && v != 1u && v != 0x3F800000u) allW = 0;
    }
    mflag = allW;
  }
  __syncthreads();
  const int wide = mflag;
  const size_t wi = (size_t)blockIdx.x * 256 + threadIdx.x;  // word index
  const size_t src0 = wi * 64;                               // first element idx
  u64 bits = 0ull;
  if (!wide) {  // u8 bool storage
    const uint4* p = reinterpret_cast<const uint4*>(mask8 + src0);
#pragma unroll
    for (int q = 0; q < 4; ++q) {
      const uint4 v = p[q];
      const unsigned vv[4] = {v.x, v.y, v.z, v.w};
#pragma unroll
      for (int k = 0; k < 4; ++k) {
        unsigned tt = vv[k];
        tt |= tt >> 4; tt |= tt >> 2; tt |= tt >> 1;
        tt &= 0x01010101u;
        const unsigned nib =
            (tt & 1u) | ((tt >> 7) & 2u) | ((tt >> 14) & 4u) | ((tt >> 21) & 8u);
        bits |= (u64)nib << (q * 16 + k * 4);
      }
    }
  } else {  // 4-byte storage: nonzero word => masked
    const unsigned* p = reinterpret_cast<const unsigned*>(mask8) + src0;
#pragma unroll
    for (int k = 0; k < 64; ++k)
      bits |= (u64)(p[k] != 0u) << k;
  }
  mb[wi] = bits;
}

// ---------------- GEMM (m97 pattern): C = A * BT^T (+bias, epilogues) -------
// Linear LDS [128][32], global_load_lds width-16, ds_read_b128 fragments.
// EPI==0: C -> bf16 (projections, z=0,1,2). EPI==1: C+resid -> f32 (final).
template <int EPI>
__global__ __launch_bounds__(256) void gemm_bt(
    const u16* __restrict__ A0, const u16* __restrict__ B0,
    const float* __restrict__ bias0, const float* __restrict__ bias1,
    const float* __restrict__ bias2, u16* __restrict__ Obf,
    float* __restrict__ Of, const float* __restrict__ resid) {
  __shared__ __align__(16) u16 As[128 * 32];  // 64B per row, linear (gload_lds dest)
  __shared__ __align__(16) u16 Bs[128 * 32];
  const int z = blockIdx.z;
  const u16* A = A0 + (size_t)z * MD;
  const u16* Bt = B0 + (size_t)z * DD;
  const float* bias = (z == 0) ? bias0 : ((z == 1) ? bias1 : bias2);
  const int t = threadIdx.x;
  const int m0 = blockIdx.y * 128, n0 = blockIdx.x * 128;
  const int w = t >> 6, lane = t & 63, lr = lane & 15, lk = lane >> 4;
  const int wm = (w >> 1) * 64, wn = (w & 1) * 64;
  const int srow = lane >> 2, scol = (lane & 3) * 8;  // within 16-row chunk

  f32x4 acc[4][4] = {};

  for (int k0 = 0; k0 < 1024; k0 += 32) {
    __syncthreads();  // previous iter's fragment reads done before overwrite
#pragma unroll
    for (int it = 0; it < 2; ++it) {
      const int c = w * 2 + it;  // chunk = 16 rows; wave-uniform LDS base
      gload_lds16(A + (size_t)(m0 + 16 * c + srow) * 1024 + k0 + scol,
                  &As[c * 512 + lane * 8]);
      gload_lds16(Bt + (size_t)(n0 + 16 * c + srow) * 1024 + k0 + scol,
                  &Bs[c * 512 + lane * 8]);
    }
    __syncthreads();  // barrier drain waits vmcnt(0): LDS tiles ready
    bf16x8 af[4], bfr[4];
#pragma unroll
    for (int i = 0; i < 4; ++i)
      af[i] = *reinterpret_cast<const bf16x8*>(&As[(wm + i * 16 + lr) * 32 + lk * 8]);
#pragma unroll
    for (int j = 0; j < 4; ++j)
      bfr[j] = *reinterpret_cast<const bf16x8*>(&Bs[(wn + j * 16 + lr) * 32 + lk * 8]);
#pragma unroll
    for (int i = 0; i < 4; ++i) {
#pragma unroll
      for (int j = 0; j < 4; ++j)
        acc[i][j] = MFMA_BF16(af[i], bfr[j], acc[i][j]);
    }
  }

#pragma unroll
  for (int i = 0; i < 4; ++i) {
#pragma unroll
    for (int j = 0; j < 4; ++j) {
#pragma unroll
      for (int r = 0; r < 4; ++r) {
        const int row = m0 + wm + i * 16 + lk * 4 + r;  // C/D: row=(lane>>4)*4+reg
        const int col = n0 + wn + j * 16 + lr;          //       col=lane&15
        const float v = acc[i][j][r] + bias[col];
        if constexpr (EPI == 0) {
          Obf[(size_t)z * MD + (size_t)row * 1024 + col] = f2bf(v);
        } else {
          const size_t idx = (size_t)row * 1024 + col;
          Of[idx] = v + resid[idx];
        }
      }
    }
  }
}

// ---------------- V head-transpose: Vt[bh][f][p'] bf16 ----------------
__global__ __launch_bounds__(256) void vt_k(const u16* __restrict__ VP,
                                            u16* __restrict__ VTo) {
  __shared__ __align__(16) u16 tile[64][72];
  const int t = threadIdx.x;
  const int bh = blockIdx.y, p0 = blockIdx.x * 64;
  const int b = bh >> 4, shi = bh & 15;
  const size_t hb = (size_t)b * 1048576 + (size_t)shi * 65536;
#pragma unroll
  for (int it = 0; it < 2; ++it) {
    const int c = t + it * 256;
    const int row = c >> 3, f8 = (c & 7) * 8;
    const int p = p0 + row;
    *reinterpret_cast<int4*>(&tile[row][f8]) = *reinterpret_cast<const int4*>(
        VP + hb + (size_t)(p >> 4) * 1024 + (p & 15) * 64 + f8);
  }
  __syncthreads();
#pragma unroll
  for (int it = 0; it < 2; ++it) {
    const int c = t + it * 256;
    const int f = c >> 3, pc = (c & 7) * 8;
    __align__(16) u16 tmp[8];
#pragma unroll
    for (int i = 0; i < 8; ++i) tmp[i] = tile[pc + i][f];
    *reinterpret_cast<int4*>(VTo + (size_t)bh * 65536 + (size_t)f * 1024 + p0 + pc) =
        *reinterpret_cast<int4*>(tmp);
  }
}

// ---------------- fused attention, single-pass, 32-row blocks ----------------
// Grid (32, 128): qt = blockIdx.x FAST (L2 working set ~2 heads/XCD), bh = .y.
// 512 threads (8 waves), 2 blocks/CU. Block = 32 q-rows.
// Phase 1: wave w does kt=2w,2w+1; K frags loaded once per kt, reused for both
// 16-row groups. S^T = mfma(K,Q), p = exp2(fma(s,SCL,mask?-inf:0)) -> swizzled
// Ps (LDS, (q,k) at Ps[q*1024 + (k^((q&7)<<3))]); per-row sums in registers.
// One barrier. Phase 2: PV (wave = 16 rows x 16 cols), ctx normalized.
// Phase 3: attnOut = Ps * rinv, coalesced nontemporal f32x4.
__global__ __launch_bounds__(512, 4) void attn_k(
    const u16* __restrict__ QP, const u16* __restrict__ KP,
    const u16* __restrict__ VT, const u64* __restrict__ mb,
    float* __restrict__ attnOut, u16* __restrict__ ctx) {
  __shared__ __align__(16) u16 Ps[32 * 1024];   // 64 KiB
  __shared__ float red[8][2][16];

  const int t = threadIdx.x;
  const int qt = blockIdx.x;
  const int bh = blockIdx.y;
  const int q0 = qt * 32;
  const int b = bh >> 4, shi = bh & 15;
  const size_t hb = (size_t)b * 1048576 + (size_t)shi * 65536;
  const u64* mrow = mb + (size_t)(shi & 7) * 16384;  // [1024][16] words

  const int w = t >> 6, lane = t & 63, lr = lane & 15, lk = lane >> 4;
  const int qsw = (lr & 7) << 3;  // swizzle term (q-row low bits = lr&7)

  // Q fragments for both row groups: lane holds Q[q0+rg*16+lr][kd*32+lk*8+e]
  bf16x8 qf[2][2];
#pragma unroll
  for (int rg = 0; rg < 2; ++rg) {
    const u16* qb = QP + hb + (size_t)(qt * 2 + rg) * 1024 + lr * 64 + lk * 8;
    qf[rg][0] = *reinterpret_cast<const bf16x8*>(qb);
    qf[rg][1] = *reinterpret_cast<const bf16x8*>(qb + 32);
  }

  float psum[2] = {0.f, 0.f};

  // ---- phase 1: wave w handles kt = 2w, 2w+1 ----
#pragma unroll
  for (int ki = 0; ki < 2; ++ki) {
    const int kt = w * 2 + ki;
    const u16* kb = KP + hb + (size_t)(kt * 4) * 1024 + lr * 64 + lk * 8;
    bf16x8 kf[4][2];
#pragma unroll
    for (int j = 0; j < 4; ++j) {
      kf[j][0] = *reinterpret_cast<const bf16x8*>(kb + j * 1024);
      kf[j][1] = *reinterpret_cast<const bf16x8*>(kb + j * 1024 + 32);
    }
#pragma unroll
    for (int rg = 0; rg < 2; ++rg) {
      f32x4 sf[4];
#pragma unroll
      for (int j = 0; j < 4; ++j) {
        f32x4 a = {};
        a = MFMA_BF16(kf[j][0], qf[rg][0], a);
        a = MFMA_BF16(kf[j][1], qf[rg][1], a);
        sf[j] = a;  // S[k = kt*64+j*16+lk*4+r][q-row rg*16+lr]
      }
      const u64 mw = mrow[(size_t)(q0 + rg * 16 + lr) * 16 + kt];
#pragma unroll
      for (int j = 0; j < 4; ++j) {
        u16 pb[4];
#pragma unroll
        for (int r = 0; r < 4; ++r) {
          const unsigned bit = (unsigned)(mw >> (j * 16 + lk * 4 + r)) & 1u;
          const float sel = bit ? -__builtin_inff() : 0.0f;
          const float p = __builtin_amdgcn_exp2f(fmaf(sf[j][r], SCL, sel));
          psum[rg] += p;
          pb[r] = f2bf(p);
        }
        const unsigned lo = (unsigned)pb[0] | ((unsigned)pb[1] << 16);
        const unsigned hi = (unsigned)pb[2] | ((unsigned)pb[3] << 16);
        const int kel = (kt * 64 + j * 16 + lk * 4) ^ qsw;
        *reinterpret_cast<u64*>(&Ps[(rg * 16 + lr) * 1024 + kel]) =
            (u64)lo | ((u64)hi << 32);
      }
    }
  }
  // per-row partial sums (this wave's 128-k slice) -> red[w][rg][row]
#pragma unroll
  for (int rg = 0; rg < 2; ++rg) {
    psum[rg] += __shfl_xor(psum[rg], 16, 64);
    psum[rg] += __shfl_xor(psum[rg], 32, 64);
  }
  if (lane < 16) { red[w][0][lr] = psum[0]; red[w][1][lr] = psum[1]; }
  __syncthreads();

  // ---- phase 2: PV. wave w -> rows (w>>2)*16.., cols (w&3)*16.. ----
  const int rbase = (w >> 2) * 16, cg = (w & 3) * 16;
  const u16* vb = VT + (size_t)bh * 65536 + (size_t)(cg + lr) * 1024 + lk * 8;
  f32x4 cacc[4] = {};  // 4 independent chains (ILP)
#pragma unroll
  for (int kk = 0; kk < 32; ++kk) {
    const int kel = (kk * 32 + lk * 8) ^ qsw;  // (rbase+lr)&7 == lr&7
    const bf16x8 pf = *reinterpret_cast<const bf16x8*>(&Ps[(rbase + lr) * 1024 + kel]);
    const bf16x8 vf = *reinterpret_cast<const bf16x8*>(vb + kk * 32);
    cacc[kk & 3] = MFMA_BF16(pf, vf, cacc[kk & 3]);
  }
#pragma unroll
  for (int r = 0; r < 4; ++r) {
    const int l16 = lk * 4 + r;
    float rs = 0.f;
#pragma unroll
    for (int w2 = 0; w2 < 8; ++w2) rs += red[w2][w >> 2][l16];
    const float ri = (rs > 0.f) ? __builtin_amdgcn_rcpf(rs) : 0.f;
    const float cv = cacc[0][r] + cacc[1][r] + cacc[2][r] + cacc[3][r];
    const int p = q0 + rbase + l16;
    ctx[hb + (size_t)(p >> 4) * 1024 + (size_t)(p & 15) * 64 + cg + lr] = f2bf(cv * ri);
  }

  // ---- phase 3: attnOut = Ps * rinv, coalesced nontemporal f32x4 ----
  const int arow = t >> 4, ac4 = (t & 15) * 4;
  const int asw = (arow & 7) << 3;
  float rsA = 0.f;
#pragma unroll
  for (int w2 = 0; w2 < 8; ++w2) rsA += red[w2][arow >> 4][arow & 15];
  const float riA = (rsA > 0.f) ? __builtin_amdgcn_rcpf(rsA) : 0.f;
  float* aout = attnOut + (size_t)bh * 1048576 + (size_t)(q0 + arow) * 1024;
#pragma unroll
  for (int i = 0; i < 16; ++i) {
    const int col = i * 64 + ac4;
    const u64 p4 = *reinterpret_cast<const u64*>(&Ps[arow * 1024 + (col ^ asw)]);
    f32x4 o;
    o[0] = bf2f((u16)(p4 & 0xffffu)) * riA;
    o[1] = bf2f((u16)((p4 >> 16) & 0xffffu)) * riA;
    o[2] = bf2f((u16)((p4 >> 32) & 0xffffu)) * riA;
    o[3] = bf2f((u16)(p4 >> 48)) * riA;
    __builtin_nontemporal_store(o, reinterpret_cast<f32x4*>(aout + col));
  }
}

// ---------------- LayerNorm over last dim (1024) ----------------
__global__ __launch_bounds__(256) void ln_k(const float* __restrict__ X,
                                            const float* __restrict__ gamma,
                                            const float* __restrict__ beta,
                                            float* __restrict__ Y) {
  const int row = blockIdx.x, t = threadIdx.x;
  const size_t base = (size_t)row * 1024;
  const float4 x = *reinterpret_cast<const float4*>(X + base + t * 4);
  float s = x.x + x.y + x.z + x.w;
  float s2 = x.x * x.x + x.y * x.y + x.z * x.z + x.w * x.w;
#pragma unroll
  for (int d = 1; d < 64; d <<= 1) {
    s += __shfl_xor(s, d, 64);
    s2 += __shfl_xor(s2, d, 64);
  }
  __shared__ float red[8];
  const int w = t >> 6;
  if ((t & 63) == 0) { red[w] = s; red[4 + w] = s2; }
  __syncthreads();
  s = red[0] + red[1] + red[2] + red[3];
  s2 = red[4] + red[5] + red[6] + red[7];
  const float mu = s * (1.f / 1024.f);
  const float var = s2 * (1.f / 1024.f) - mu * mu;
  const float inv = rsqrtf(var + 1e-5f);
  const float4 g = *reinterpret_cast<const float4*>(gamma + t * 4);
  const float4 be = *reinterpret_cast<const float4*>(beta + t * 4);
  float4 y;
  y.x = (x.x - mu) * inv * g.x + be.x;
  y.y = (x.y - mu) * inv * g.y + be.y;
  y.z = (x.z - mu) * inv * g.z + be.z;
  y.w = (x.w - mu) * inv * g.w + be.w;
  *reinterpret_cast<float4*>(Y + base + t * 4) = y;
}

extern "C" void kernel_launch(void* const* d_in, const int* in_sizes, int n_in,
                              void* d_out, int out_size, void* d_ws, size_t ws_size,
                              hipStream_t stream) {
  const float* keyF = (const float*)d_in[0];
  const float* valueF = (const float*)d_in[1];
  const float* queryF = (const float*)d_in[2];
  const unsigned char* mask8 = (const unsigned char*)d_in[3];
  const float* Wk = (const float*)d_in[4];
  const float* bk = (const float*)d_in[5];
  const float* Wv = (const float*)d_in[6];
  const float* bv = (const float*)d_in[7];
  const float* Wq = (const float*)d_in[8];
  const float* bq = (const float*)d_in[9];
  const float* Wf = (const float*)d_in[10];
  const float* bfp = (const float*)d_in[11];
  const float* gamma = (const float*)d_in[12];
  const float* beta = (const float*)d_in[13];

  char* ws = (char*)d_ws;
  // layout (bytes): [0,48M) Xbf k/v/q bf16 | [48M,56M) WT x4 | [56M,104M) K/V/Q proj
  // | [104M,120M) Vt | [120M,121M) mask bits. After projections: [0,16M) ctx,
  // [16M,48M) preLN f32.
  u16* Xbf = (u16*)(ws);
  u16* WT = (u16*)(ws + 50331648);
  u16* KP = (u16*)(ws + 58720256);
  u16* VP = (u16*)(ws + 75497472);
  u16* QP = (u16*)(ws + 92274688);
  u16* VT = (u16*)(ws + 109051904);
  u64* MB = (u64*)(ws + 125829120);
  u16* CTX = (u16*)(ws);
  float* PRELN = (float*)(ws + 16777216);

  float* outF = (float*)d_out;
  float* attnF = outF + 8388608;

  cvt_k<<<dim3(8192, 1, 3), 256, 0, stream>>>(keyF, valueF, queryF, Xbf);
  wt_k<<<dim3(32, 32, 4), 256, 0, stream>>>(Wk, Wv, Wq, Wf, WT);
  mb_k<<<dim3(512), 256, 0, stream>>>(mask8, MB);
  gemm_bt<0><<<dim3(8, 64, 3), 256, 0, stream>>>(Xbf, WT, bk, bv, bq, KP, nullptr, nullptr);
  vt_k<<<dim3(16, 128), 256, 0, stream>>>(VP, VT);
  attn_k<<<dim3(32, 128), 512, 0, stream>>>(QP, KP, VT, MB, attnF, CTX);
  gemm_bt<1><<<dim3(8, 64, 1), 256, 0, stream>>>(CTX, WT + 3 * DD, bfp, bfp, bfp,
                                                 nullptr, PRELN, queryF);
  ln_k<<<dim3(8192), 256, 0, stream>>>(PRELN, gamma, beta, outF);
}

// Round 8
// 338.129 us; speedup vs baseline: 1.4582x; 1.1785x over previous
//
#include <hip/hip_runtime.h>

// B=8 S=1024 D=1024 H=16 DH=64.
// Head bh=b*16+s_hi (s_hi=s>>6); head elem (p,f) -> proj[b][s_hi*64+(p>>4)][(p&15)*64+f].
// mask index for head bh is s_hi&7. scale=0.5 (=> exp2 domain: 0.5*log2e).

typedef unsigned short u16;
typedef unsigned long long u64;
typedef __attribute__((ext_vector_type(8))) short bf16x8;
typedef __attribute__((ext_vector_type(4))) float f32x4;

#define MFMA_BF16(a, b, c) __builtin_amdgcn_mfma_f32_16x16x32_bf16((a), (b), (c), 0, 0, 0)

__device__ __forceinline__ u16 f2bf(float f) {
  unsigned u = __float_as_uint(f);
  u += 0x7fffu + ((u >> 16) & 1u);   // round-nearest-even
  return (u16)(u >> 16);
}
__device__ __forceinline__ float bf2f(u16 b) {
  return __uint_as_float(((unsigned)b) << 16);
}
__device__ __forceinline__ unsigned cvt_pk_bf16(float lo, float hi) {
  unsigned r;
  asm("v_cvt_pk_bf16_f32 %0, %1, %2" : "=v"(r) : "v"(lo), "v"(hi));
  return r;
}
__device__ __forceinline__ void gload_lds16(const u16* g, u16* l) {
  __builtin_amdgcn_global_load_lds(
      (const __attribute__((address_space(1))) void*)g,
      (__attribute__((address_space(3))) void*)l, 16, 0, 0);
}

static constexpr size_t MD = 8192ull * 1024ull;  // one [B,S,D] tensor, elements
static constexpr size_t DD = 1024ull * 1024ull;  // one [D,D] weight, elements
static constexpr float SCL = 0.72134752044f;     // 0.5 * log2(e)

// ---------------- f32 -> bf16 for key/value/query ----------------
__global__ __launch_bounds__(256) void cvt_k(const float* __restrict__ K,
                                             const float* __restrict__ V,
                                             const float* __restrict__ Q,
                                             u16* __restrict__ O) {
  const int z = blockIdx.z;
  const float* src = (z == 0) ? K : ((z == 1) ? V : Q);
  const size_t i = ((size_t)blockIdx.x * 256 + threadIdx.x) * 4;
  const float4 v = *reinterpret_cast<const float4*>(src + i);
  ushort4 o;
  o.x = f2bf(v.x); o.y = f2bf(v.y); o.z = f2bf(v.z); o.w = f2bf(v.w);
  *reinterpret_cast<ushort4*>(O + (size_t)z * MD + i) = o;
}

// ---------------- W[K,N] f32 -> WT[N,K] bf16, for Wk,Wv,Wq,Wf ----------------
__global__ __launch_bounds__(256) void wt_k(const float* __restrict__ Wk,
                                            const float* __restrict__ Wv,
                                            const float* __restrict__ Wq,
                                            const float* __restrict__ Wf,
                                            u16* __restrict__ WT) {
  const int z = blockIdx.z;
  const float* W = (z == 0) ? Wk : ((z == 1) ? Wv : ((z == 2) ? Wq : Wf));
  __shared__ float tile[32][33];
  const int k0 = blockIdx.y * 32, n0 = blockIdx.x * 32;
  const int r = threadIdx.x >> 5, c = threadIdx.x & 31;
#pragma unroll
  for (int rr = r; rr < 32; rr += 8)
    tile[rr][c] = W[(size_t)(k0 + rr) * 1024 + n0 + c];
  __syncthreads();
#pragma unroll
  for (int rr = r; rr < 32; rr += 8)
    WT[(size_t)z * DD + (size_t)(n0 + rr) * 1024 + k0 + c] = f2bf(tile[c][rr]);
}

// ---------------- mask -> bit-packed u64 words: mb[8][1024][16] ----------------
__global__ __launch_bounds__(256) void mb_k(const unsigned char* __restrict__ mask8,
                                            u64* __restrict__ mb) {
  __shared__ int mflag;
  if (threadIdx.x == 0) {
    const unsigned* mw = reinterpret_cast<const unsigned*>(mask8);
    int allW = 1;  // storage is 4-byte words (int32 0/1 or f32 0.0/1.0)?
    for (int i = 0; i < 64; ++i) {
      const unsigned v = mw[i];
      if (v != 0u && v != 1u && v != 0x3F800000u) allW = 0;
    }
    mflag = allW;
  }
  __syncthreads();
  const int wide = mflag;
  const size_t wi = (size_t)blockIdx.x * 256 + threadIdx.x;  // word index
  const size_t src0 = wi * 64;                               // first element idx
  u64 bits = 0ull;
  if (!wide) {  // u8 bool storage
    const uint4* p = reinterpret_cast<const uint4*>(mask8 + src0);
#pragma unroll
    for (int q = 0; q < 4; ++q) {
      const uint4 v = p[q];
      const unsigned vv[4] = {v.x, v.y, v.z, v.w};
#pragma unroll
      for (int k = 0; k < 4; ++k) {
        unsigned tt = vv[k];
        tt |= tt >> 4; tt |= tt >> 2; tt |= tt >> 1;
        tt &= 0x01010101u;
        const unsigned nib =
            (tt & 1u) | ((tt >> 7) & 2u) | ((tt >> 14) & 4u) | ((tt >> 21) & 8u);
        bits |= (u64)nib << (q * 16 + k * 4);
      }
    }
  } else {  // 4-byte storage: nonzero word => masked
    const unsigned* p = reinterpret_cast<const unsigned*>(mask8) + src0;
#pragma unroll
    for (int k = 0; k < 64; ++k)
      bits |= (u64)(p[k] != 0u) << k;
  }
  mb[wi] = bits;
}

// ---------------- GEMM (m97 pattern): C = A * BT^T (+bias, epilogues) -------
// Linear LDS [128][32], global_load_lds width-16, ds_read_b128 fragments.
// EPI==0: C -> bf16 (projections, z=0,1,2). EPI==1: C+resid -> bf16 (preLN).
template <int EPI>
__global__ __launch_bounds__(256) void gemm_bt(
    const u16* __restrict__ A0, const u16* __restrict__ B0,
    const float* __restrict__ bias0, const float* __restrict__ bias1,
    const float* __restrict__ bias2, u16* __restrict__ Obf,
    const float* __restrict__ resid) {
  __shared__ __align__(16) u16 As[128 * 32];  // 64B per row, linear (gload_lds dest)
  __shared__ __align__(16) u16 Bs[128 * 32];
  const int z = blockIdx.z;
  const u16* A = A0 + (size_t)z * MD;
  const u16* Bt = B0 + (size_t)z * DD;
  const float* bias = (z == 0) ? bias0 : ((z == 1) ? bias1 : bias2);
  const int t = threadIdx.x;
  const int m0 = blockIdx.y * 128, n0 = blockIdx.x * 128;
  const int w = t >> 6, lane = t & 63, lr = lane & 15, lk = lane >> 4;
  const int wm = (w >> 1) * 64, wn = (w & 1) * 64;
  const int srow = lane >> 2, scol = (lane & 3) * 8;  // within 16-row chunk

  f32x4 acc[4][4] = {};

  for (int k0 = 0; k0 < 1024; k0 += 32) {
    __syncthreads();  // previous iter's fragment reads done before overwrite
#pragma unroll
    for (int it = 0; it < 2; ++it) {
      const int c = w * 2 + it;  // chunk = 16 rows; wave-uniform LDS base
      gload_lds16(A + (size_t)(m0 + 16 * c + srow) * 1024 + k0 + scol,
                  &As[c * 512 + lane * 8]);
      gload_lds16(Bt + (size_t)(n0 + 16 * c + srow) * 1024 + k0 + scol,
                  &Bs[c * 512 + lane * 8]);
    }
    __syncthreads();  // barrier drain waits vmcnt(0): LDS tiles ready
    bf16x8 af[4], bfr[4];
#pragma unroll
    for (int i = 0; i < 4; ++i)
      af[i] = *reinterpret_cast<const bf16x8*>(&As[(wm + i * 16 + lr) * 32 + lk * 8]);
#pragma unroll
    for (int j = 0; j < 4; ++j)
      bfr[j] = *reinterpret_cast<const bf16x8*>(&Bs[(wn + j * 16 + lr) * 32 + lk * 8]);
#pragma unroll
    for (int i = 0; i < 4; ++i) {
#pragma unroll
      for (int j = 0; j < 4; ++j)
        acc[i][j] = MFMA_BF16(af[i], bfr[j], acc[i][j]);
    }
  }

#pragma unroll
  for (int i = 0; i < 4; ++i) {
#pragma unroll
    for (int j = 0; j < 4; ++j) {
#pragma unroll
      for (int r = 0; r < 4; ++r) {
        const int row = m0 + wm + i * 16 + lk * 4 + r;  // C/D: row=(lane>>4)*4+reg
        const int col = n0 + wn + j * 16 + lr;          //       col=lane&15
        const size_t idx = (size_t)row * 1024 + col;
        const float v = acc[i][j][r] + bias[col];
        if constexpr (EPI == 0) {
          Obf[(size_t)z * MD + idx] = f2bf(v);
        } else {
          Obf[idx] = f2bf(v + resid[idx]);
        }
      }
    }
  }
}

// ---------------- V head-transpose: Vt[bh][f][p'] bf16 ----------------
__global__ __launch_bounds__(256) void vt_k(const u16* __restrict__ VP,
                                            u16* __restrict__ VTo) {
  __shared__ __align__(16) u16 tile[64][72];
  const int t = threadIdx.x;
  const int bh = blockIdx.y, p0 = blockIdx.x * 64;
  const int b = bh >> 4, shi = bh & 15;
  const size_t hb = (size_t)b * 1048576 + (size_t)shi * 65536;
#pragma unroll
  for (int it = 0; it < 2; ++it) {
    const int c = t + it * 256;
    const int row = c >> 3, f8 = (c & 7) * 8;
    const int p = p0 + row;
    *reinterpret_cast<int4*>(&tile[row][f8]) = *reinterpret_cast<const int4*>(
        VP + hb + (size_t)(p >> 4) * 1024 + (p & 15) * 64 + f8);
  }
  __syncthreads();
#pragma unroll
  for (int it = 0; it < 2; ++it) {
    const int c = t + it * 256;
    const int f = c >> 3, pc = (c & 7) * 8;
    __align__(16) u16 tmp[8];
#pragma unroll
    for (int i = 0; i < 8; ++i) tmp[i] = tile[pc + i][f];
    *reinterpret_cast<int4*>(VTo + (size_t)bh * 65536 + (size_t)f * 1024 + p0 + pc) =
        *reinterpret_cast<int4*>(tmp);
  }
}

// ---------------- fused attention, single-pass, wave-specialized tail --------
// Grid (32, 128): qt = blockIdx.x FAST (L2 working set ~2 heads/XCD), bh = .y.
// 512 threads (8 waves), 2 blocks/CU. Block = 32 q-rows.
// Phase 1 (all 8 waves): wave w does kt=2w,2w+1, both 16-row groups; K frags
// loaded once per kt. p = exp2(fma(s,SCL,mask?-inf:0)) unnormalized -> swizzled
// Ps via v_cvt_pk_bf16_f32; per-row partial sums -> red. One barrier.
// Tail: waves 0-3 do PV (V frags shared across both row groups) + ctx;
// waves 4-7 CONCURRENTLY stream attnOut = Ps * rinv (1 row / iteration,
// conflict-free LDS reads, nontemporal stores) -> overlaps HBM drain with MFMA.
__global__ __launch_bounds__(512, 4) void attn_k(
    const u16* __restrict__ QP, const u16* __restrict__ KP,
    const u16* __restrict__ VT, const u64* __restrict__ mb,
    float* __restrict__ attnOut, u16* __restrict__ ctx) {
  __shared__ __align__(16) u16 Ps[32 * 1024];   // 64 KiB
  __shared__ float red[8][2][16];

  const int t = threadIdx.x;
  const int qt = blockIdx.x;
  const int bh = blockIdx.y;
  const int q0 = qt * 32;
  const int b = bh >> 4, shi = bh & 15;
  const size_t hb = (size_t)b * 1048576 + (size_t)shi * 65536;
  const u64* mrow = mb + (size_t)(shi & 7) * 16384;  // [1024][16] words

  const int w = t >> 6, lane = t & 63, lr = lane & 15, lk = lane >> 4;
  const int qsw = (lr & 7) << 3;  // swizzle term (q-row low bits = lr&7)

  // Q fragments for both row groups: lane holds Q[q0+rg*16+lr][kd*32+lk*8+e]
  bf16x8 qf[2][2];
#pragma unroll
  for (int rg = 0; rg < 2; ++rg) {
    const u16* qb = QP + hb + (size_t)(qt * 2 + rg) * 1024 + lr * 64 + lk * 8;
    qf[rg][0] = *reinterpret_cast<const bf16x8*>(qb);
    qf[rg][1] = *reinterpret_cast<const bf16x8*>(qb + 32);
  }

  float psum[2] = {0.f, 0.f};

  // ---- phase 1: wave w handles kt = 2w, 2w+1 ----
#pragma unroll
  for (int ki = 0; ki < 2; ++ki) {
    const int kt = w * 2 + ki;
    const u16* kb = KP + hb + (size_t)(kt * 4) * 1024 + lr * 64 + lk * 8;
    bf16x8 kf[4][2];
#pragma unroll
    for (int j = 0; j < 4; ++j) {
      kf[j][0] = *reinterpret_cast<const bf16x8*>(kb + j * 1024);
      kf[j][1] = *reinterpret_cast<const bf16x8*>(kb + j * 1024 + 32);
    }
#pragma unroll
    for (int rg = 0; rg < 2; ++rg) {
      f32x4 sf[4];
#pragma unroll
      for (int j = 0; j < 4; ++j) {
        f32x4 a = {};
        a = MFMA_BF16(kf[j][0], qf[rg][0], a);
        a = MFMA_BF16(kf[j][1], qf[rg][1], a);
        sf[j] = a;  // S[k = kt*64+j*16+lk*4+r][q-row rg*16+lr]
      }
      const u64 mw = mrow[(size_t)(q0 + rg * 16 + lr) * 16 + kt];
#pragma unroll
      for (int j = 0; j < 4; ++j) {
        float p[4];
#pragma unroll
        for (int r = 0; r < 4; ++r) {
          const unsigned bit = (unsigned)(mw >> (j * 16 + lk * 4 + r)) & 1u;
          const float sel = bit ? -__builtin_inff() : 0.0f;
          p[r] = __builtin_amdgcn_exp2f(fmaf(sf[j][r], SCL, sel));
          psum[rg] += p[r];
        }
        const unsigned lo = cvt_pk_bf16(p[0], p[1]);
        const unsigned hi = cvt_pk_bf16(p[2], p[3]);
        const int kel = (kt * 64 + j * 16 + lk * 4) ^ qsw;
        *reinterpret_cast<u64*>(&Ps[(rg * 16 + lr) * 1024 + kel]) =
            (u64)lo | ((u64)hi << 32);
      }
    }
  }
  // per-row partial sums (this wave's 128-k slice) -> red[w][rg][row]
#pragma unroll
  for (int rg = 0; rg < 2; ++rg) {
    psum[rg] += __shfl_xor(psum[rg], 16, 64);
    psum[rg] += __shfl_xor(psum[rg], 32, 64);
  }
  if (lane < 16) { red[w][0][lr] = psum[0]; red[w][1][lr] = psum[1]; }
  __syncthreads();

  // per-lane rinv for rows 0..31 (lane L holds rinv of local row L), shfl-broadcast
  float rsl = 0.f;
  if (lane < 32) {
#pragma unroll
    for (int w2 = 0; w2 < 8; ++w2) rsl += red[w2][lane >> 4][lane & 15];
  }
  const float rinvl = (rsl > 0.f) ? __builtin_amdgcn_rcpf(rsl) : 0.f;

  if (w < 4) {
    // ---- PV (waves 0-3): wave w -> ctx cols w*16..+15, both row groups ----
    const int cg = w * 16;
    const u16* vb = VT + (size_t)bh * 65536 + (size_t)(cg + lr) * 1024 + lk * 8;
    f32x4 cacc[2][2] = {};  // [rg][kk&1] independent chains
#pragma unroll
    for (int kk = 0; kk < 32; ++kk) {
      const int kel = (kk * 32 + lk * 8) ^ qsw;
      const bf16x8 vf = *reinterpret_cast<const bf16x8*>(vb + kk * 32);
      const bf16x8 pf0 = *reinterpret_cast<const bf16x8*>(&Ps[lr * 1024 + kel]);
      const bf16x8 pf1 = *reinterpret_cast<const bf16x8*>(&Ps[(16 + lr) * 1024 + kel]);
      cacc[0][kk & 1] = MFMA_BF16(pf0, vf, cacc[0][kk & 1]);
      cacc[1][kk & 1] = MFMA_BF16(pf1, vf, cacc[1][kk & 1]);
    }
#pragma unroll
    for (int rg = 0; rg < 2; ++rg) {
#pragma unroll
      for (int r = 0; r < 4; ++r) {
        const int lrow = rg * 16 + lk * 4 + r;
        const float ri = __shfl(rinvl, lrow, 64);
        const float cv = cacc[rg][0][r] + cacc[rg][1][r];
        const int p = q0 + lrow;
        ctx[hb + (size_t)(p >> 4) * 1024 + (size_t)(p & 15) * 64 + cg + lr] =
            f2bf(cv * ri);
      }
    }
  } else {
    // ---- stores (waves 4-7): attnOut row i per iteration, 256 threads ----
    const int t2 = t - 256;  // 0..255; thread covers cols t2*4..+3
    float* aout = attnOut + (size_t)bh * 1048576 + (size_t)q0 * 1024;
#pragma unroll
    for (int i = 0; i < 32; ++i) {
      const int asw = (i & 7) << 3;
      const float ri = __shfl(rinvl, i, 64);
      const u64 p4 = *reinterpret_cast<const u64*>(&Ps[i * 1024 + ((t2 * 4) ^ asw)]);
      f32x4 o;
      o[0] = bf2f((u16)(p4 & 0xffffu)) * ri;
      o[1] = bf2f((u16)((p4 >> 16) & 0xffffu)) * ri;
      o[2] = bf2f((u16)((p4 >> 32) & 0xffffu)) * ri;
      o[3] = bf2f((u16)(p4 >> 48)) * ri;
      __builtin_nontemporal_store(
          o, reinterpret_cast<f32x4*>(aout + (size_t)i * 1024 + t2 * 4));
    }
  }
}

// ---------------- LayerNorm over last dim (1024), bf16 input ----------------
__global__ __launch_bounds__(256) void ln_k(const u16* __restrict__ X,
                                            const float* __restrict__ gamma,
                                            const float* __restrict__ beta,
                                            float* __restrict__ Y) {
  const int row = blockIdx.x, t = threadIdx.x;
  const size_t base = (size_t)row * 1024;
  const u64 xw = *reinterpret_cast<const u64*>(X + base + t * 4);
  float x0 = bf2f((u16)(xw & 0xffffu));
  float x1 = bf2f((u16)((xw >> 16) & 0xffffu));
  float x2 = bf2f((u16)((xw >> 32) & 0xffffu));
  float x3 = bf2f((u16)(xw >> 48));
  float s = x0 + x1 + x2 + x3;
  float s2 = x0 * x0 + x1 * x1 + x2 * x2 + x3 * x3;
#pragma unroll
  for (int d = 1; d < 64; d <<= 1) {
    s += __shfl_xor(s, d, 64);
    s2 += __shfl_xor(s2, d, 64);
  }
  __shared__ float red[8];
  const int w = t >> 6;
  if ((t & 63) == 0) { red[w] = s; red[4 + w] = s2; }
  __syncthreads();
  s = red[0] + red[1] + red[2] + red[3];
  s2 = red[4] + red[5] + red[6] + red[7];
  const float mu = s * (1.f / 1024.f);
  const float var = s2 * (1.f / 1024.f) - mu * mu;
  const float inv = rsqrtf(var + 1e-5f);
  const float4 g = *reinterpret_cast<const float4*>(gamma + t * 4);
  const float4 be = *reinterpret_cast<const float4*>(beta + t * 4);
  float4 y;
  y.x = (x0 - mu) * inv * g.x + be.x;
  y.y = (x1 - mu) * inv * g.y + be.y;
  y.z = (x2 - mu) * inv * g.z + be.z;
  y.w = (x3 - mu) * inv * g.w + be.w;
  *reinterpret_cast<float4*>(Y + base + t * 4) = y;
}

extern "C" void kernel_launch(void* const* d_in, const int* in_sizes, int n_in,
                              void* d_out, int out_size, void* d_ws, size_t ws_size,
                              hipStream_t stream) {
  const float* keyF = (const float*)d_in[0];
  const float* valueF = (const float*)d_in[1];
  const float* queryF = (const float*)d_in[2];
  const unsigned char* mask8 = (const unsigned char*)d_in[3];
  const float* Wk = (const float*)d_in[4];
  const float* bk = (const float*)d_in[5];
  const float* Wv = (const float*)d_in[6];
  const float* bv = (const float*)d_in[7];
  const float* Wq = (const float*)d_in[8];
  const float* bq = (const float*)d_in[9];
  const float* Wf = (const float*)d_in[10];
  const float* bfp = (const float*)d_in[11];
  const float* gamma = (const float*)d_in[12];
  const float* beta = (const float*)d_in[13];

  char* ws = (char*)d_ws;
  // layout (bytes): [0,48M) Xbf k/v/q bf16 | [48M,56M) WT x4 | [56M,104M) K/V/Q proj
  // | [104M,120M) Vt | [120M,121M) mask bits. After projections: [0,16M) ctx,
  // [16M,32M) preLN bf16.
  u16* Xbf = (u16*)(ws);
  u16* WT = (u16*)(ws + 50331648);
  u16* KP = (u16*)(ws + 58720256);
  u16* VP = (u16*)(ws + 75497472);
  u16* QP = (u16*)(ws + 92274688);
  u16* VT = (u16*)(ws + 109051904);
  u64* MB = (u64*)(ws + 125829120);
  u16* CTX = (u16*)(ws);
  u16* PRELN = (u16*)(ws + 16777216);

  float* outF = (float*)d_out;
  float* attnF = outF + 8388608;

  cvt_k<<<dim3(8192, 1, 3), 256, 0, stream>>>(keyF, valueF, queryF, Xbf);
  wt_k<<<dim3(32, 32, 4), 256, 0, stream>>>(Wk, Wv, Wq, Wf, WT);
  mb_k<<<dim3(512), 256, 0, stream>>>(mask8, MB);
  gemm_bt<0><<<dim3(8, 64, 3), 256, 0, stream>>>(Xbf, WT, bk, bv, bq, KP, nullptr);
  vt_k<<<dim3(16, 128), 256, 0, stream>>>(VP, VT);
  attn_k<<<dim3(32, 128), 512, 0, stream>>>(QP, KP, VT, MB, attnF, CTX);
  gemm_bt<1><<<dim3(8, 64, 1), 256, 0, stream>>>(CTX, WT + 3 * DD, bfp, bfp, bfp,
                                                 PRELN, queryF);
  ln_k<<<dim3(8192), 256, 0, stream>>>(PRELN, gamma, beta, outF);
}